// Round 5
// baseline (337.004 us; speedup 1.0000x reference)
//
#include <hip/hip_runtime.h>

#define S_  2048
#define H_  16
#define D_  64
#define HD_ (H_ * D_)
#define SC_ 0.18033688f   // (1/8)*log2(e): folded into K at prepack; exp via exp2

using bf16x8 = __attribute__((ext_vector_type(8))) __bf16;
using bf16x4 = __attribute__((ext_vector_type(4))) __bf16;
using f32x4  = __attribute__((ext_vector_type(4))) float;

__device__ __forceinline__ f32x4 mfma16(bf16x8 a, bf16x8 b, f32x4 c) {
    return __builtin_amdgcn_mfma_f32_16x16x32_bf16(a, b, c, 0, 0, 0);
}

// async global->LDS DMA, 16B/lane; lds dest = wave-uniform base + lane*16
__device__ __forceinline__ void glds16(const void* g, void* l) {
    __builtin_amdgcn_global_load_lds((const __attribute__((address_space(1))) void*)g,
                                     (__attribute__((address_space(3))) void*)l, 16, 0, 0);
}

// ---------- prepass: K*sc -> [BH,S,D] bf16 ; V -> [BH,D,S] bf16 ----------
__global__ __launch_bounds__(256, 4)
void prepack(const float* __restrict__ Kg, const float* __restrict__ Vg,
             __bf16* __restrict__ Kb, __bf16* __restrict__ Vtb) {
    __shared__ __bf16 T[64 * 66];
    const int tid = threadIdx.x;
    const int st  = blockIdx.x;
    const int bh  = blockIdx.y;
    const int b = bh >> 4, h = bh & 15;
    if (blockIdx.z == 0) {
#pragma unroll
        for (int rep = 0; rep < 4; ++rep) {
            int lin = rep * 256 + tid;
            int r  = lin >> 4;
            int dq = (lin & 15) << 2;
            float4 x = *(const float4*)(Kg + ((size_t)(b * S_ + st * 64 + r) * H_ + h) * D_ + dq);
            bf16x4 u = {(__bf16)(x.x * SC_), (__bf16)(x.y * SC_),
                        (__bf16)(x.z * SC_), (__bf16)(x.w * SC_)};
            *(bf16x4*)(Kb + ((size_t)bh * S_ + st * 64 + r) * D_ + dq) = u;
        }
    } else {
#pragma unroll
        for (int rep = 0; rep < 4; ++rep) {
            int lin = rep * 256 + tid;
            int r  = lin >> 4;
            int dq = (lin & 15) << 2;
            float4 x = *(const float4*)(Vg + ((size_t)(b * S_ + st * 64 + r) * H_ + h) * D_ + dq);
            T[r * 66 + dq + 0] = (__bf16)x.x;
            T[r * 66 + dq + 1] = (__bf16)x.y;
            T[r * 66 + dq + 2] = (__bf16)x.z;
            T[r * 66 + dq + 3] = (__bf16)x.w;
        }
        __syncthreads();
#pragma unroll
        for (int rep = 0; rep < 4; ++rep) {
            int lin = rep * 256 + tid;
            int d  = lin >> 4;
            int s4 = (lin & 15) << 2;
            bf16x4 u = {T[(s4 + 0) * 66 + d], T[(s4 + 1) * 66 + d],
                        T[(s4 + 2) * 66 + d], T[(s4 + 3) * 66 + d]};
            *(bf16x4*)(Vtb + ((size_t)bh * D_ + d) * S_ + st * 64 + s4) = u;
        }
    }
}

// ---------- main: paired q-tiles, Bc=64, DMA double-buffered, XOR-swizzled LDS ----------
// Tile layouts (chunks of 8 bf16 = 16B): row*64 els + ((chunk ^ (row&7))*8)
__global__ __launch_bounds__(256, 4)
void fa_fwd(const float* __restrict__ Qg,
            const __bf16* __restrict__ Kb, const __bf16* __restrict__ Vtb,
            float* __restrict__ Og) {
    __shared__ __align__(16) __bf16 Kbuf[2][4096];   // 64 keys x 64 d
    __shared__ __align__(16) __bf16 Vbuf[2][4096];   // 64 d x 64 keys
    __shared__ __align__(16) __bf16 Ps[4096];        // 64 rows x 64 keys (per-wave 16 rows)

    const int tid  = threadIdx.x;
    const int lane = tid & 63;
    const int wave = tid >> 6;
    const int l16  = lane & 15;
    const int quad = lane >> 4;
    const int l8   = lane & 7;
    const int lh3  = lane >> 3;
    const int sw   = l16 & 7;            // frag-read swizzle key

    const int p   = blockIdx.x;          // pair id 0..15
    const int tHi = 31 - p;
    const int tLo = p;
    const int bh  = blockIdx.y;
    const int b   = bh >> 4;
    const int h   = bh & 15;

    // ---- DMA source pointers (element offsets; swizzled lane->global mapping) ----
    // per wave: rows wave*16..+15, two glds16 each for K and V (8 rows per op)
    const __bf16* kdma = Kb  + ((size_t)bh * S_ + wave * 16 + lh3) * D_ + ((l8 ^ lh3) << 3);
    const __bf16* vdma = Vtb + ((size_t)bh * D_ + wave * 16 + lh3) * S_ + ((l8 ^ lh3) << 3);

    // prime tile 0 into buf 0
    glds16(kdma,          &Kbuf[0][wave * 1024]);
    glds16(kdma + 8 * D_, &Kbuf[0][wave * 1024 + 512]);
    glds16(vdma,          &Vbuf[0][wave * 1024]);
    glds16(vdma + 8 * S_, &Vbuf[0][wave * 1024 + 512]);

    // ---- Q fragments from fp32 global (latency overlaps the priming DMA) ----
    const size_t qbase = (size_t)b * S_ * HD_ + (size_t)h * D_;
    const float* Qp = Qg + qbase;
    float*       Op = Og + qbase;
    bf16x8 qh[2], ql[2];
#pragma unroll
    for (int kf = 0; kf < 2; ++kf) {
        const float* qph = Qp + (size_t)(tHi * 64 + wave * 16 + l16) * HD_ + quad * 8 + kf * 32;
        const float* qpl = Qp + (size_t)(tLo * 64 + wave * 16 + l16) * HD_ + quad * 8 + kf * 32;
        float4 x = *(const float4*)(qph);
        float4 y = *(const float4*)(qph + 4);
        bf16x8 f;
        f[0] = (__bf16)x.x; f[1] = (__bf16)x.y; f[2] = (__bf16)x.z; f[3] = (__bf16)x.w;
        f[4] = (__bf16)y.x; f[5] = (__bf16)y.y; f[6] = (__bf16)y.z; f[7] = (__bf16)y.w;
        qh[kf] = f;
        x = *(const float4*)(qpl);
        y = *(const float4*)(qpl + 4);
        f[0] = (__bf16)x.x; f[1] = (__bf16)x.y; f[2] = (__bf16)x.z; f[3] = (__bf16)x.w;
        f[4] = (__bf16)y.x; f[5] = (__bf16)y.y; f[6] = (__bf16)y.z; f[7] = (__bf16)y.w;
        ql[kf] = f;
    }

    bf16x8 ones;
#pragma unroll
    for (int j = 0; j < 8; ++j) ones[j] = (__bf16)1.0f;

    f32x4 oh[4], ol[4], lh, ll;
#pragma unroll
    for (int nd = 0; nd < 4; ++nd) { oh[nd] = (f32x4)0.f; ol[nd] = (f32x4)0.f; }
    lh = (f32x4)0.f; ll = (f32x4)0.f;

    // softmax + P pack + PV + l-MFMA for one 64x64 score block (this wave: 16 rows)
    auto process = [&](f32x4* s, bool diag, f32x4* oacc, f32x4& lacc, int cb) {
        if (diag) {                       // wave-uniform branch, 2 iters per tile
#pragma unroll
            for (int nt = 0; nt < 4; ++nt)
#pragma unroll
                for (int r = 0; r < 4; ++r)
                    if (nt * 16 + l16 > wave * 16 + quad * 4 + r) s[nt][r] = -1e30f;
        }
#pragma unroll
        for (int nt = 0; nt < 4; ++nt)
#pragma unroll
            for (int r = 0; r < 4; ++r)
                s[nt][r] = __builtin_amdgcn_exp2f(s[nt][r]);
        // P -> Ps: row = wave*16+quad*4+r, col = nt*16+l16, swizzled chunk
        const int row0 = wave * 16 + quad * 4;
        const int ch   = l16 >> 3;       // col chunk low bit
        const int e    = l16 & 7;
#pragma unroll
        for (int r = 0; r < 4; ++r) {
            const int rw = (row0 + r) & 7;
            __bf16* pw = &Ps[(row0 + r) * 64 + e];
#pragma unroll
            for (int nt = 0; nt < 4; ++nt)
                pw[((nt * 2 + ch) ^ rw) << 3] = (__bf16)s[nt][r];
        }
        // A-frags: row' = wave*16+l16, k-chunks (kf*4+quad)^sw
        const __bf16* pr = &Ps[(wave * 16 + l16) * 64];
        bf16x8 a0 = *(const bf16x8*)&pr[((0 + quad) ^ sw) << 3];
        bf16x8 a1 = *(const bf16x8*)&pr[((4 + quad) ^ sw) << 3];
#pragma unroll
        for (int nd = 0; nd < 4; ++nd) {
            const __bf16* vr = &Vbuf[cb][(nd * 16 + l16) * 64];
            bf16x8 bv0 = *(const bf16x8*)&vr[((0 + quad) ^ sw) << 3];
            bf16x8 bv1 = *(const bf16x8*)&vr[((4 + quad) ^ sw) << 3];
            oacc[nd] = mfma16(a0, bv0, oacc[nd]);
            oacc[nd] = mfma16(a1, bv1, oacc[nd]);
        }
        lacc = mfma16(a0, ones, lacc);   // row-sums of P (all cols equal)
        lacc = mfma16(a1, ones, lacc);
    };

    const int nkt = 32 - p;              // hi: all tiles; lo active while kt<=p
    __syncthreads();                     // tile 0 DMA drained
    for (int kt = 0; kt < nkt; ++kt) {
        const int cb = kt & 1;
        if (kt + 1 < nkt) {
            const __bf16* kp = kdma + (size_t)(kt + 1) * 4096;
            const __bf16* vp = vdma + (kt + 1) * 64;
            glds16(kp,          &Kbuf[cb ^ 1][wave * 1024]);
            glds16(kp + 8 * D_, &Kbuf[cb ^ 1][wave * 1024 + 512]);
            glds16(vp,          &Vbuf[cb ^ 1][wave * 1024]);
            glds16(vp + 8 * S_, &Vbuf[cb ^ 1][wave * 1024 + 512]);
        }
        const bool loAct = (kt <= p);
        f32x4 sh[4], sl[4];
#pragma unroll
        for (int nt = 0; nt < 4; ++nt) { sh[nt] = (f32x4)0.f; sl[nt] = (f32x4)0.f; }
#pragma unroll
        for (int nt = 0; nt < 4; ++nt) {
            const __bf16* kr = &Kbuf[cb][(nt * 16 + l16) * 64];
#pragma unroll
            for (int kf = 0; kf < 2; ++kf) {
                bf16x8 bk = *(const bf16x8*)&kr[(((kf << 2) + quad) ^ sw) << 3];
                sh[nt] = mfma16(qh[kf], bk, sh[nt]);
                if (loAct) sl[nt] = mfma16(ql[kf], bk, sl[nt]);
            }
        }
        process(sh, kt == tHi, oh, lh, cb);
        if (loAct) process(sl, kt == tLo, ol, ll, cb);
        __syncthreads();
    }

    // ---- epilogue: O /= l (l from ones-MFMA; no shuffles needed) ----
    auto finish = [&](f32x4* oacc, f32x4& lacc, int trow) {
#pragma unroll
        for (int r = 0; r < 4; ++r) {
            float inv = 1.0f / lacc[r];
            float* op = Op + (size_t)(trow * 64 + wave * 16 + quad * 4 + r) * HD_;
#pragma unroll
            for (int nd = 0; nd < 4; ++nd)
                op[nd * 16 + l16] = oacc[nd][r] * inv;
        }
    };
    finish(oh, lh, tHi);
    finish(ol, ll, tLo);
}

// ---------- fallback (round-3 kernel) if ws too small ----------
#define LDAF 66
#define LDPF 68
__global__ __launch_bounds__(256, 4)
void fa_fwd_fb(const float* __restrict__ Qg, const float* __restrict__ Kg,
               const float* __restrict__ Vg, float* __restrict__ Og) {
    __shared__ __bf16 Ks[64 * LDAF];
    __shared__ __bf16 Vt[64 * LDAF];
    __shared__ __bf16 Psf[4 * 16 * LDPF];
    const int tid = threadIdx.x, lane = tid & 63, wave = tid >> 6;
    const int l16 = lane & 15, quad = lane >> 4;
    const int p = blockIdx.x, tHi = 31 - p, tLo = p;
    const int bh = blockIdx.y, b = bh >> 4, h = bh & 15;
    const size_t base = (size_t)b * S_ * HD_ + (size_t)h * D_;
    const float* Qp = Qg + base; const float* Kp = Kg + base;
    const float* Vp = Vg + base; float* Op = Og + base;
    bf16x8 qh[2], ql[2];
#pragma unroll
    for (int kf = 0; kf < 2; ++kf) {
        const float* qph = Qp + (size_t)(tHi * 64 + wave * 16 + l16) * HD_ + quad * 8 + kf * 32;
        const float* qpl = Qp + (size_t)(tLo * 64 + wave * 16 + l16) * HD_ + quad * 8 + kf * 32;
        float4 x = *(const float4*)(qph); float4 y = *(const float4*)(qph + 4);
        bf16x8 f;
        f[0]=(__bf16)x.x; f[1]=(__bf16)x.y; f[2]=(__bf16)x.z; f[3]=(__bf16)x.w;
        f[4]=(__bf16)y.x; f[5]=(__bf16)y.y; f[6]=(__bf16)y.z; f[7]=(__bf16)y.w;
        qh[kf] = f;
        x = *(const float4*)(qpl); y = *(const float4*)(qpl + 4);
        f[0]=(__bf16)x.x; f[1]=(__bf16)x.y; f[2]=(__bf16)x.z; f[3]=(__bf16)x.w;
        f[4]=(__bf16)y.x; f[5]=(__bf16)y.y; f[6]=(__bf16)y.z; f[7]=(__bf16)y.w;
        ql[kf] = f;
    }
    f32x4 oh[4], ol[4]; float lh[4], ll[4];
#pragma unroll
    for (int nd = 0; nd < 4; ++nd) { oh[nd] = (f32x4)0.f; ol[nd] = (f32x4)0.f; }
#pragma unroll
    for (int r = 0; r < 4; ++r) { lh[r] = 0.f; ll[r] = 0.f; }
    auto process = [&](f32x4* s, bool diag, f32x4* oacc, float* lsum) {
#pragma unroll
        for (int nt = 0; nt < 4; ++nt)
#pragma unroll
            for (int r = 0; r < 4; ++r) {
                float v = s[nt][r] * SC_;
                if (diag && (nt * 16 + l16 > wave * 16 + quad * 4 + r)) v = -1e30f;
                float pe = __builtin_amdgcn_exp2f(v);
                s[nt][r] = pe; lsum[r] += pe;
            }
        __bf16* pw = &Psf[(wave * 16 + quad * 4) * LDPF + l16];
#pragma unroll
        for (int r = 0; r < 4; ++r)
#pragma unroll
            for (int nt = 0; nt < 4; ++nt) pw[r * LDPF + nt * 16] = (__bf16)s[nt][r];
        const __bf16* pr = &Psf[wave * 16 * LDPF];
#pragma unroll
        for (int kf = 0; kf < 2; ++kf) {
            bf16x8 a = *(const bf16x8*)&pr[l16 * LDPF + kf * 32 + quad * 8];
#pragma unroll
            for (int nd = 0; nd < 4; ++nd) {
                bf16x8 bv = *(const bf16x8*)&Vt[(nd * 16 + l16) * LDAF + kf * 32 + quad * 8];
                oacc[nd] = mfma16(a, bv, oacc[nd]);
            }
        }
    };
    const int nkt = 32 - p;
    for (int kt = 0; kt < nkt; ++kt) {
        __syncthreads();
#pragma unroll
        for (int rep = 0; rep < 4; ++rep) {
            int linear = rep * 256 + tid;
            int key = linear >> 4; int dq = (linear & 15) << 2;
            const float* kp = Kp + (size_t)(kt * 64 + key) * HD_ + dq;
            const float* vp = Vp + (size_t)(kt * 64 + key) * HD_ + dq;
            float4 kv = *(const float4*)kp; float4 vv = *(const float4*)vp;
            __bf16* kd = &Ks[key * LDAF + dq];
            kd[0]=(__bf16)kv.x; kd[1]=(__bf16)kv.y; kd[2]=(__bf16)kv.z; kd[3]=(__bf16)kv.w;
            Vt[(dq+0)*LDAF+key]=(__bf16)vv.x; Vt[(dq+1)*LDAF+key]=(__bf16)vv.y;
            Vt[(dq+2)*LDAF+key]=(__bf16)vv.z; Vt[(dq+3)*LDAF+key]=(__bf16)vv.w;
        }
        __syncthreads();
        const bool loAct = (kt <= p);
        f32x4 sh[4], sl[4];
#pragma unroll
        for (int nt = 0; nt < 4; ++nt) { sh[nt] = (f32x4)0.f; sl[nt] = (f32x4)0.f; }
#pragma unroll
        for (int nt = 0; nt < 4; ++nt)
#pragma unroll
            for (int kf = 0; kf < 2; ++kf) {
                bf16x8 bf = *(const bf16x8*)&Ks[(nt * 16 + l16) * LDAF + kf * 32 + quad * 8];
                sh[nt] = mfma16(qh[kf], bf, sh[nt]);
                if (loAct) sl[nt] = mfma16(ql[kf], bf, sl[nt]);
            }
        process(sh, kt == tHi, oh, lh);
        if (loAct) process(sl, kt == tLo, ol, ll);
    }
    auto finish = [&](f32x4* oacc, float* lsum, int trow) {
#pragma unroll
        for (int r = 0; r < 4; ++r) {
            float s = lsum[r];
            s += __shfl_xor(s, 1); s += __shfl_xor(s, 2);
            s += __shfl_xor(s, 4); s += __shfl_xor(s, 8);
            float inv = 1.0f / s;
            float* op = Op + (size_t)(trow * 64 + wave * 16 + quad * 4 + r) * HD_;
#pragma unroll
            for (int nd = 0; nd < 4; ++nd) op[nd * 16 + l16] = oacc[nd][r] * inv;
        }
    };
    finish(oh, lh, tHi); finish(ol, ll, tLo);
}

extern "C" void kernel_launch(void* const* d_in, const int* in_sizes, int n_in,
                              void* d_out, int out_size, void* d_ws, size_t ws_size,
                              hipStream_t stream) {
    const float* q = (const float*)d_in[0];
    const float* k = (const float*)d_in[1];
    const float* v = (const float*)d_in[2];
    float*       o = (float*)d_out;
    const size_t NEL  = (size_t)4 * H_ * S_ * D_;
    const size_t NEED = 2 * NEL * sizeof(__bf16);
    if (ws_size >= NEED) {
        __bf16* Kb  = (__bf16*)d_ws;
        __bf16* Vtb = Kb + NEL;
        dim3 pgrid(S_ / 64, 4 * H_, 2);
        prepack<<<pgrid, 256, 0, stream>>>(k, v, Kb, Vtb);
        dim3 grid(16, 4 * H_);
        fa_fwd<<<grid, 256, 0, stream>>>(q, Kb, Vtb, o);
    } else {
        dim3 grid(16, 4 * H_);
        fa_fwd_fb<<<grid, 256, 0, stream>>>(q, k, v, o);
    }
}

// Round 6
// 190.107 us; speedup vs baseline: 1.7727x; 1.7727x over previous
//
#include <hip/hip_runtime.h>

#define S_  2048
#define H_  16
#define D_  64
#define HD_ (H_ * D_)
#define SC_ 0.18033688f   // (1/8)*log2(e): folded into K at prepack; exp via exp2
#define LDP 40            // Ps row stride (els): 80 B rows -> 16B-aligned b128 A-frag reads

using bf16x8 = __attribute__((ext_vector_type(8))) __bf16;
using bf16x4 = __attribute__((ext_vector_type(4))) __bf16;
using f32x4  = __attribute__((ext_vector_type(4))) float;

__device__ __forceinline__ f32x4 mfma16(bf16x8 a, bf16x8 b, f32x4 c) {
    return __builtin_amdgcn_mfma_f32_16x16x32_bf16(a, b, c, 0, 0, 0);
}

// async global->LDS DMA, 16B/lane; lds dest = wave-uniform base + lane*16
__device__ __forceinline__ void glds16(const void* g, void* l) {
    __builtin_amdgcn_global_load_lds((const __attribute__((address_space(1))) void*)g,
                                     (__attribute__((address_space(3))) void*)l, 16, 0, 0);
}

// ---------- prepass: K*sc -> [BH,S,D] bf16 ; V -> [BH,D,S] bf16 ----------
__global__ __launch_bounds__(256, 4)
void prepack(const float* __restrict__ Kg, const float* __restrict__ Vg,
             __bf16* __restrict__ Kb, __bf16* __restrict__ Vtb) {
    __shared__ __bf16 T[64 * 66];
    const int tid = threadIdx.x;
    const int st  = blockIdx.x;
    const int bh  = blockIdx.y;
    const int b = bh >> 4, h = bh & 15;
    if (blockIdx.z == 0) {
#pragma unroll
        for (int rep = 0; rep < 4; ++rep) {
            int lin = rep * 256 + tid;
            int r  = lin >> 4;
            int dq = (lin & 15) << 2;
            float4 x = *(const float4*)(Kg + ((size_t)(b * S_ + st * 64 + r) * H_ + h) * D_ + dq);
            bf16x4 u = {(__bf16)(x.x * SC_), (__bf16)(x.y * SC_),
                        (__bf16)(x.z * SC_), (__bf16)(x.w * SC_)};
            *(bf16x4*)(Kb + ((size_t)bh * S_ + st * 64 + r) * D_ + dq) = u;
        }
    } else {
#pragma unroll
        for (int rep = 0; rep < 4; ++rep) {
            int lin = rep * 256 + tid;
            int r  = lin >> 4;
            int dq = (lin & 15) << 2;
            float4 x = *(const float4*)(Vg + ((size_t)(b * S_ + st * 64 + r) * H_ + h) * D_ + dq);
            T[r * 66 + dq + 0] = (__bf16)x.x;
            T[r * 66 + dq + 1] = (__bf16)x.y;
            T[r * 66 + dq + 2] = (__bf16)x.z;
            T[r * 66 + dq + 3] = (__bf16)x.w;
        }
        __syncthreads();
#pragma unroll
        for (int rep = 0; rep < 4; ++rep) {
            int lin = rep * 256 + tid;
            int d  = lin >> 4;
            int s4 = (lin & 15) << 2;
            bf16x4 u = {T[(s4 + 0) * 66 + d], T[(s4 + 1) * 66 + d],
                        T[(s4 + 2) * 66 + d], T[(s4 + 3) * 66 + d]};
            *(bf16x4*)(Vtb + ((size_t)bh * D_ + d) * S_ + st * 64 + s4) = u;
        }
    }
}

// ---------- main: round-4 structure (Bc=32, DMA dbuf) + VALU cuts + XCD swizzle ----------
__global__ __launch_bounds__(256, 4)
void fa_fwd(const float* __restrict__ Qg,
            const __bf16* __restrict__ Kb, const __bf16* __restrict__ Vtb,
            float* __restrict__ Og) {
    // K tile: 32 keys x 64 d, chunk(16B) = key*8 + (dchunk ^ (key&7))   [swizzled]
    // V tile: 64 d x 32 keys, chunk     = d*4   + (kc    ^ (d&3))       [swizzled]
    __shared__ __align__(16) __bf16 Kbuf[2][2048];
    __shared__ __align__(16) __bf16 Vbuf[2][2048];
    __shared__ __align__(16) __bf16 Ps[2560];        // 4 waves x 16 rows x LDP

    const int tid  = threadIdx.x;
    const int lane = tid & 63;
    const int wave = tid >> 6;
    const int l16  = lane & 15;
    const int quad = lane >> 4;

    // XCD-clustering decode: all 16 pair-blocks of one bh share lin%8 (-> one XCD
    // under round-robin dispatch), so that bh's 2MB K/V stays in one 4MB L2.
    const int lin = blockIdx.x;
    const int bh  = (lin & 7) + ((lin >> 3) & 7) * 8;   // 0..63
    const int p   = lin >> 6;                           // pair id 0..15
    const int tHi = 31 - p;
    const int tLo = p;
    const int b   = bh >> 4;
    const int h   = bh & 15;

    // ---- DMA source pointers (element offsets; swizzled lane->global mapping) ----
    const int kl = lane >> 3, ksl = lane & 7;            // K: 8 keys x 8 dchunks / wave
    const __bf16* kdma = Kb + ((size_t)bh * S_ + wave * 8 + kl) * D_ + ((ksl ^ kl) << 3);
    const int dl = lane >> 2, vsl = lane & 3;            // V: 16 d x 4 kchunks / wave
    const __bf16* vdma = Vtb + ((size_t)bh * D_ + wave * 16 + dl) * S_ + ((vsl ^ (dl & 3)) << 3);

    // prime tile 0 into buf 0
    glds16(kdma, &Kbuf[0][wave * 512]);
    glds16(vdma, &Vbuf[0][wave * 512]);

    // ---- Q fragments from fp32 global (latency overlaps the priming DMA) ----
    const size_t qbase = (size_t)b * S_ * HD_ + (size_t)h * D_;
    const float* Qp = Qg + qbase;
    float*       Op = Og + qbase;
    bf16x8 qh[2], ql[2];
#pragma unroll
    for (int kf = 0; kf < 2; ++kf) {
        const float* qph = Qp + (size_t)(tHi * 64 + wave * 16 + l16) * HD_ + quad * 8 + kf * 32;
        const float* qpl = Qp + (size_t)(tLo * 64 + wave * 16 + l16) * HD_ + quad * 8 + kf * 32;
        float4 x = *(const float4*)(qph);
        float4 y = *(const float4*)(qph + 4);
        bf16x8 f;
        f[0] = (__bf16)x.x; f[1] = (__bf16)x.y; f[2] = (__bf16)x.z; f[3] = (__bf16)x.w;
        f[4] = (__bf16)y.x; f[5] = (__bf16)y.y; f[6] = (__bf16)y.z; f[7] = (__bf16)y.w;
        qh[kf] = f;
        x = *(const float4*)(qpl);
        y = *(const float4*)(qpl + 4);
        f[0] = (__bf16)x.x; f[1] = (__bf16)x.y; f[2] = (__bf16)x.z; f[3] = (__bf16)x.w;
        f[4] = (__bf16)y.x; f[5] = (__bf16)y.y; f[6] = (__bf16)y.z; f[7] = (__bf16)y.w;
        ql[kf] = f;
    }

    bf16x8 ones;
#pragma unroll
    for (int j = 0; j < 8; ++j) ones[j] = (__bf16)1.0f;

    f32x4 oh[4], ol[4], lh, ll;
#pragma unroll
    for (int nd = 0; nd < 4; ++nd) { oh[nd] = (f32x4)0.f; ol[nd] = (f32x4)0.f; }
    lh = (f32x4)0.f; ll = (f32x4)0.f;

    // exp + P pack + PV + l-MFMA for one 64x32 score block (scale pre-folded into K)
    auto process = [&](f32x4* s, bool diag, int dOff, f32x4* oacc, f32x4& lacc, int cb) {
        if (diag) {                      // wave-uniform branch: 2 of ~49 iters
#pragma unroll
            for (int nt = 0; nt < 2; ++nt)
#pragma unroll
                for (int r = 0; r < 4; ++r)
                    if (dOff + nt * 16 + l16 > wave * 16 + quad * 4 + r) s[nt][r] = -1e30f;
        }
#pragma unroll
        for (int nt = 0; nt < 2; ++nt)
#pragma unroll
            for (int r = 0; r < 4; ++r)
                s[nt][r] = __builtin_amdgcn_exp2f(s[nt][r]);
        __bf16* pw = &Ps[(wave * 16 + quad * 4) * LDP + l16];
#pragma unroll
        for (int r = 0; r < 4; ++r)
#pragma unroll
            for (int nt = 0; nt < 2; ++nt)
                pw[r * LDP + nt * 16] = (__bf16)s[nt][r];
        bf16x8 a = *(const bf16x8*)&Ps[(wave * 16 + l16) * LDP + quad * 8];
#pragma unroll
        for (int nd = 0; nd < 4; ++nd) {
            bf16x8 bv = *(const bf16x8*)&Vbuf[cb][(nd * 16 + l16) * 32 + ((quad ^ (l16 & 3)) << 3)];
            oacc[nd] = mfma16(a, bv, oacc[nd]);
        }
        lacc = mfma16(a, ones, lacc);    // row-sums of P: l accumulates on the MFMA pipe
    };

    const int nkt = 64 - 2 * p;          // hi: all tiles; lo active kt < 2p+2
    __syncthreads();                     // tile 0 DMA drained
    for (int kt = 0; kt < nkt; ++kt) {
        const int cb = kt & 1;
        if (kt + 1 < nkt) {              // prefetch next tile into other buffer
            glds16(kdma + (size_t)(kt + 1) * 2048, &Kbuf[cb ^ 1][wave * 512]);
            glds16(vdma + (kt + 1) * 32,           &Vbuf[cb ^ 1][wave * 512]);
        }
        const bool loAct = (kt < 2 * p + 2);
        f32x4 sh[2], sl[2];
#pragma unroll
        for (int nt = 0; nt < 2; ++nt) { sh[nt] = (f32x4)0.f; sl[nt] = (f32x4)0.f; }
#pragma unroll
        for (int nt = 0; nt < 2; ++nt)
#pragma unroll
            for (int kf = 0; kf < 2; ++kf) {
                bf16x8 bk = *(const bf16x8*)&Kbuf[cb][(nt * 16 + l16) * 64 +
                                 ((((kf << 2) + quad) ^ (l16 & 7)) << 3)];
                sh[nt] = mfma16(qh[kf], bk, sh[nt]);
                if (loAct) sl[nt] = mfma16(ql[kf], bk, sl[nt]);
            }
        process(sh, kt >= 2 * tHi, kt * 32 - tHi * 64, oh, lh, cb);
        if (loAct) process(sl, kt >= 2 * tLo, kt * 32 - tLo * 64, ol, ll, cb);
        __syncthreads();                 // next tile landed + all reads of cb done
    }

    // ---- epilogue: O /= l (l from ones-MFMA; no shuffles) ----
    auto finish = [&](f32x4* oacc, f32x4& lacc, int trow) {
#pragma unroll
        for (int r = 0; r < 4; ++r) {
            float inv = 1.0f / lacc[r];
            float* op = Op + (size_t)(trow * 64 + wave * 16 + quad * 4 + r) * HD_;
#pragma unroll
            for (int nd = 0; nd < 4; ++nd)
                op[nd * 16 + l16] = oacc[nd][r] * inv;
        }
    };
    finish(oh, lh, tHi);
    finish(ol, ll, tLo);
}

// ---------- fallback (round-3 kernel) if ws too small ----------
#define LDAF 66
#define LDPF 68
__global__ __launch_bounds__(256, 4)
void fa_fwd_fb(const float* __restrict__ Qg, const float* __restrict__ Kg,
               const float* __restrict__ Vg, float* __restrict__ Og) {
    __shared__ __bf16 Ks[64 * LDAF];
    __shared__ __bf16 Vt[64 * LDAF];
    __shared__ __bf16 Psf[4 * 16 * LDPF];
    const int tid = threadIdx.x, lane = tid & 63, wave = tid >> 6;
    const int l16 = lane & 15, quad = lane >> 4;
    const int p = blockIdx.x & 15, tHi = 31 - p, tLo = p;
    const int bh = blockIdx.x >> 4, b = bh >> 4, h = bh & 15;
    const size_t base = (size_t)b * S_ * HD_ + (size_t)h * D_;
    const float* Qp = Qg + base; const float* Kp = Kg + base;
    const float* Vp = Vg + base; float* Op = Og + base;
    bf16x8 qh[2], ql[2];
#pragma unroll
    for (int kf = 0; kf < 2; ++kf) {
        const float* qph = Qp + (size_t)(tHi * 64 + wave * 16 + l16) * HD_ + quad * 8 + kf * 32;
        const float* qpl = Qp + (size_t)(tLo * 64 + wave * 16 + l16) * HD_ + quad * 8 + kf * 32;
        float4 x = *(const float4*)(qph); float4 y = *(const float4*)(qph + 4);
        bf16x8 f;
        f[0]=(__bf16)x.x; f[1]=(__bf16)x.y; f[2]=(__bf16)x.z; f[3]=(__bf16)x.w;
        f[4]=(__bf16)y.x; f[5]=(__bf16)y.y; f[6]=(__bf16)y.z; f[7]=(__bf16)y.w;
        qh[kf] = f;
        x = *(const float4*)(qpl); y = *(const float4*)(qpl + 4);
        f[0]=(__bf16)x.x; f[1]=(__bf16)x.y; f[2]=(__bf16)x.z; f[3]=(__bf16)x.w;
        f[4]=(__bf16)y.x; f[5]=(__bf16)y.y; f[6]=(__bf16)y.z; f[7]=(__bf16)y.w;
        ql[kf] = f;
    }
    f32x4 oh[4], ol[4]; float lh[4], ll[4];
#pragma unroll
    for (int nd = 0; nd < 4; ++nd) { oh[nd] = (f32x4)0.f; ol[nd] = (f32x4)0.f; }
#pragma unroll
    for (int r = 0; r < 4; ++r) { lh[r] = 0.f; ll[r] = 0.f; }
    auto process = [&](f32x4* s, bool diag, f32x4* oacc, float* lsum) {
#pragma unroll
        for (int nt = 0; nt < 4; ++nt)
#pragma unroll
            for (int r = 0; r < 4; ++r) {
                float v = s[nt][r] * SC_;
                if (diag && (nt * 16 + l16 > wave * 16 + quad * 4 + r)) v = -1e30f;
                float pe = __builtin_amdgcn_exp2f(v);
                s[nt][r] = pe; lsum[r] += pe;
            }
        __bf16* pw = &Psf[(wave * 16 + quad * 4) * LDPF + l16];
#pragma unroll
        for (int r = 0; r < 4; ++r)
#pragma unroll
            for (int nt = 0; nt < 4; ++nt) pw[r * LDPF + nt * 16] = (__bf16)s[nt][r];
        const __bf16* pr = &Psf[wave * 16 * LDPF];
#pragma unroll
        for (int kf = 0; kf < 2; ++kf) {
            bf16x8 a = *(const bf16x8*)&pr[l16 * LDPF + kf * 32 + quad * 8];
#pragma unroll
            for (int nd = 0; nd < 4; ++nd) {
                bf16x8 bv = *(const bf16x8*)&Vt[(nd * 16 + l16) * LDAF + kf * 32 + quad * 8];
                oacc[nd] = mfma16(a, bv, oacc[nd]);
            }
        }
    };
    const int nkt = 32 - p;
    for (int kt = 0; kt < nkt; ++kt) {
        __syncthreads();
#pragma unroll
        for (int rep = 0; rep < 4; ++rep) {
            int linear = rep * 256 + tid;
            int key = linear >> 4; int dq = (linear & 15) << 2;
            const float* kp = Kp + (size_t)(kt * 64 + key) * HD_ + dq;
            const float* vp = Vp + (size_t)(kt * 64 + key) * HD_ + dq;
            float4 kv = *(const float4*)kp; float4 vv = *(const float4*)vp;
            __bf16* kd = &Ks[key * LDAF + dq];
            kd[0]=(__bf16)kv.x; kd[1]=(__bf16)kv.y; kd[2]=(__bf16)kv.z; kd[3]=(__bf16)kv.w;
            Vt[(dq+0)*LDAF+key]=(__bf16)vv.x; Vt[(dq+1)*LDAF+key]=(__bf16)vv.y;
            Vt[(dq+2)*LDAF+key]=(__bf16)vv.z; Vt[(dq+3)*LDAF+key]=(__bf16)vv.w;
        }
        __syncthreads();
        const bool loAct = (kt <= p);
        f32x4 sh[4], sl[4];
#pragma unroll
        for (int nt = 0; nt < 4; ++nt) { sh[nt] = (f32x4)0.f; sl[nt] = (f32x4)0.f; }
#pragma unroll
        for (int nt = 0; nt < 4; ++nt)
#pragma unroll
            for (int kf = 0; kf < 2; ++kf) {
                bf16x8 bf = *(const bf16x8*)&Ks[(nt * 16 + l16) * LDAF + kf * 32 + quad * 8];
                sh[nt] = mfma16(qh[kf], bf, sh[nt]);
                if (loAct) sl[nt] = mfma16(ql[kf], bf, sl[nt]);
            }
        process(sh, kt == tHi, oh, lh);
        if (loAct) process(sl, kt == tLo, ol, ll);
    }
    auto finish = [&](f32x4* oacc, float* lsum, int trow) {
#pragma unroll
        for (int r = 0; r < 4; ++r) {
            float s = lsum[r];
            s += __shfl_xor(s, 1); s += __shfl_xor(s, 2);
            s += __shfl_xor(s, 4); s += __shfl_xor(s, 8);
            float inv = 1.0f / s;
            float* op = Op + (size_t)(trow * 64 + wave * 16 + quad * 4 + r) * HD_;
#pragma unroll
            for (int nd = 0; nd < 4; ++nd) op[nd * 16 + l16] = oacc[nd][r] * inv;
        }
    };
    finish(oh, lh, tHi); finish(ol, ll, tLo);
}

extern "C" void kernel_launch(void* const* d_in, const int* in_sizes, int n_in,
                              void* d_out, int out_size, void* d_ws, size_t ws_size,
                              hipStream_t stream) {
    const float* q = (const float*)d_in[0];
    const float* k = (const float*)d_in[1];
    const float* v = (const float*)d_in[2];
    float*       o = (float*)d_out;
    const size_t NEL  = (size_t)4 * H_ * S_ * D_;
    const size_t NEED = 2 * NEL * sizeof(__bf16);
    if (ws_size >= NEED) {
        __bf16* Kb  = (__bf16*)d_ws;
        __bf16* Vtb = Kb + NEL;
        dim3 pgrid(S_ / 64, 4 * H_, 2);
        prepack<<<pgrid, 256, 0, stream>>>(k, v, Kb, Vtb);
        fa_fwd<<<dim3(1024), 256, 0, stream>>>(q, Kb, Vtb, o);
    } else {
        fa_fwd_fb<<<dim3(1024), 256, 0, stream>>>(q, k, v, o);
    }
}

// Round 7
// 180.592 us; speedup vs baseline: 1.8661x; 1.0527x over previous
//
#include <hip/hip_runtime.h>

#define S_  2048
#define H_  16
#define D_  64
#define HD_ (H_ * D_)
#define SC_ 0.18033688f   // (1/8)*log2(e): folded into K at prepack; exp via exp2
#define LDP 40            // Ps row stride (els): 80 B rows; b64 writes 2-way (free), b128 reads aligned

using bf16x8 = __attribute__((ext_vector_type(8))) __bf16;
using bf16x4 = __attribute__((ext_vector_type(4))) __bf16;
using f32x4  = __attribute__((ext_vector_type(4))) float;

__device__ __forceinline__ f32x4 mfma16(bf16x8 a, bf16x8 b, f32x4 c) {
    return __builtin_amdgcn_mfma_f32_16x16x32_bf16(a, b, c, 0, 0, 0);
}

// async global->LDS DMA, 16B/lane; lds dest = wave-uniform base + lane*16
__device__ __forceinline__ void glds16(const void* g, void* l) {
    __builtin_amdgcn_global_load_lds((const __attribute__((address_space(1))) void*)g,
                                     (__attribute__((address_space(3))) void*)l, 16, 0, 0);
}

// ---------- prepass: K*sc -> [BH,S,D] bf16 ; V -> [BH,D,S] bf16 ----------
__global__ __launch_bounds__(256, 4)
void prepack(const float* __restrict__ Kg, const float* __restrict__ Vg,
             __bf16* __restrict__ Kb, __bf16* __restrict__ Vtb) {
    __shared__ __bf16 T[64 * 66];
    const int tid = threadIdx.x;
    const int st  = blockIdx.x;
    const int bh  = blockIdx.y;
    const int b = bh >> 4, h = bh & 15;
    if (blockIdx.z == 0) {
#pragma unroll
        for (int rep = 0; rep < 4; ++rep) {
            int lin = rep * 256 + tid;
            int r  = lin >> 4;
            int dq = (lin & 15) << 2;
            float4 x = *(const float4*)(Kg + ((size_t)(b * S_ + st * 64 + r) * H_ + h) * D_ + dq);
            bf16x4 u = {(__bf16)(x.x * SC_), (__bf16)(x.y * SC_),
                        (__bf16)(x.z * SC_), (__bf16)(x.w * SC_)};
            *(bf16x4*)(Kb + ((size_t)bh * S_ + st * 64 + r) * D_ + dq) = u;
        }
    } else {
#pragma unroll
        for (int rep = 0; rep < 4; ++rep) {
            int lin = rep * 256 + tid;
            int r  = lin >> 4;
            int dq = (lin & 15) << 2;
            float4 x = *(const float4*)(Vg + ((size_t)(b * S_ + st * 64 + r) * H_ + h) * D_ + dq);
            T[r * 66 + dq + 0] = (__bf16)x.x;
            T[r * 66 + dq + 1] = (__bf16)x.y;
            T[r * 66 + dq + 2] = (__bf16)x.z;
            T[r * 66 + dq + 3] = (__bf16)x.w;
        }
        __syncthreads();
#pragma unroll
        for (int rep = 0; rep < 4; ++rep) {
            int lin = rep * 256 + tid;
            int d  = lin >> 4;
            int s4 = (lin & 15) << 2;
            bf16x4 u = {T[(s4 + 0) * 66 + d], T[(s4 + 1) * 66 + d],
                        T[(s4 + 2) * 66 + d], T[(s4 + 3) * 66 + d]};
            *(bf16x4*)(Vtb + ((size_t)bh * D_ + d) * S_ + st * 64 + s4) = u;
        }
    }
}

// ---------- main: round-6 structure + S^T trick (K·Q^T) + packed P writes ----------
__global__ __launch_bounds__(256, 4)
void fa_fwd(const float* __restrict__ Qg,
            const __bf16* __restrict__ Kb, const __bf16* __restrict__ Vtb,
            float* __restrict__ Og) {
    // K tile: 32 keys x 64 d, chunk(16B) = key*8 + (dchunk ^ (key&7))   [swizzled]
    // V tile: 64 d x 32 keys, chunk     = d*4   + (kc    ^ (d&3))       [swizzled]
    __shared__ __align__(16) __bf16 Kbuf[2][2048];
    __shared__ __align__(16) __bf16 Vbuf[2][2048];
    __shared__ __align__(16) __bf16 Ps[2560];        // 4 waves x 16 rows(query) x LDP (keys)

    const int tid  = threadIdx.x;
    const int lane = tid & 63;
    const int wave = tid >> 6;
    const int l16  = lane & 15;
    const int quad = lane >> 4;

    // XCD-clustering decode: all 16 pair-blocks of one bh share lin%8 (-> one XCD
    // under round-robin dispatch), so that bh's 2MB K/V stays in one 4MB L2.
    const int lin = blockIdx.x;
    const int bh  = (lin & 7) + ((lin >> 3) & 7) * 8;   // 0..63
    const int p   = lin >> 6;                           // pair id 0..15
    const int tHi = 31 - p;
    const int tLo = p;
    const int b   = bh >> 4;
    const int h   = bh & 15;

    // ---- DMA source pointers (element offsets; swizzled lane->global mapping) ----
    const int kl = lane >> 3, ksl = lane & 7;            // K: 8 keys x 8 dchunks / wave
    const __bf16* kdma = Kb + ((size_t)bh * S_ + wave * 8 + kl) * D_ + ((ksl ^ kl) << 3);
    const int dl = lane >> 2, vsl = lane & 3;            // V: 16 d x 4 kchunks / wave
    const __bf16* vdma = Vtb + ((size_t)bh * D_ + wave * 16 + dl) * S_ + ((vsl ^ (dl & 3)) << 3);

    // prime tile 0 into buf 0
    glds16(kdma, &Kbuf[0][wave * 512]);
    glds16(vdma, &Vbuf[0][wave * 512]);

    // ---- Q fragments from fp32 global (latency overlaps the priming DMA) ----
    // Content: Q[query=l16][d=quad*8+j+kf*32] — serves as the MFMA *B* operand for K·Q^T.
    const size_t qbase = (size_t)b * S_ * HD_ + (size_t)h * D_;
    const float* Qp = Qg + qbase;
    float*       Op = Og + qbase;
    bf16x8 qh[2], ql[2];
#pragma unroll
    for (int kf = 0; kf < 2; ++kf) {
        const float* qph = Qp + (size_t)(tHi * 64 + wave * 16 + l16) * HD_ + quad * 8 + kf * 32;
        const float* qpl = Qp + (size_t)(tLo * 64 + wave * 16 + l16) * HD_ + quad * 8 + kf * 32;
        float4 x = *(const float4*)(qph);
        float4 y = *(const float4*)(qph + 4);
        bf16x8 f;
        f[0] = (__bf16)x.x; f[1] = (__bf16)x.y; f[2] = (__bf16)x.z; f[3] = (__bf16)x.w;
        f[4] = (__bf16)y.x; f[5] = (__bf16)y.y; f[6] = (__bf16)y.z; f[7] = (__bf16)y.w;
        qh[kf] = f;
        x = *(const float4*)(qpl);
        y = *(const float4*)(qpl + 4);
        f[0] = (__bf16)x.x; f[1] = (__bf16)x.y; f[2] = (__bf16)x.z; f[3] = (__bf16)x.w;
        f[4] = (__bf16)y.x; f[5] = (__bf16)y.y; f[6] = (__bf16)y.z; f[7] = (__bf16)y.w;
        ql[kf] = f;
    }

    bf16x8 ones;
#pragma unroll
    for (int j = 0; j < 8; ++j) ones[j] = (__bf16)1.0f;

    f32x4 oh[4], ol[4], lh, ll;
#pragma unroll
    for (int nd = 0; nd < 4; ++nd) { oh[nd] = (f32x4)0.f; ol[nd] = (f32x4)0.f; }
    lh = (f32x4)0.f; ll = (f32x4)0.f;

    // S^T C-layout: s[mt][r] = S[key = mt*16+quad*4+r][query = l16] (keys of this kt-tile).
    // exp + packed P write + PV + l-MFMA. Scale pre-folded into K.
    auto process = [&](f32x4* s, bool diag, int dOff, f32x4* oacc, f32x4& lacc, int cb) {
        if (diag) {                      // wave-uniform branch: 2 of ~49 iters
#pragma unroll
            for (int mt = 0; mt < 2; ++mt)
#pragma unroll
                for (int r = 0; r < 4; ++r)
                    if (dOff + mt * 16 + quad * 4 + r > wave * 16 + l16) s[mt][r] = -1e30f;
        }
#pragma unroll
        for (int mt = 0; mt < 2; ++mt)
#pragma unroll
            for (int r = 0; r < 4; ++r)
                s[mt][r] = __builtin_amdgcn_exp2f(s[mt][r]);
        // P^T frag -> Ps[query][key]: lane holds 4 consecutive keys -> packed b64 stores
        __bf16* pw = &Ps[(wave * 16 + l16) * LDP + quad * 4];
        bf16x4 u0 = {(__bf16)s[0][0], (__bf16)s[0][1], (__bf16)s[0][2], (__bf16)s[0][3]};
        bf16x4 u1 = {(__bf16)s[1][0], (__bf16)s[1][1], (__bf16)s[1][2], (__bf16)s[1][3]};
        *(bf16x4*)(pw)      = u0;        // keys quad*4 .. +3
        *(bf16x4*)(pw + 16) = u1;        // keys 16+quad*4 .. +3
        // A-frag (P): A[m=query=l16][k=key=quad*8+j] — byte-identical read to round 6
        bf16x8 a = *(const bf16x8*)&Ps[(wave * 16 + l16) * LDP + quad * 8];
#pragma unroll
        for (int nd = 0; nd < 4; ++nd) {
            bf16x8 bv = *(const bf16x8*)&Vbuf[cb][(nd * 16 + l16) * 32 + ((quad ^ (l16 & 3)) << 3)];
            oacc[nd] = mfma16(a, bv, oacc[nd]);
        }
        lacc = mfma16(a, ones, lacc);    // row-sums of P on the MFMA pipe
    };

    const int nkt = 64 - 2 * p;          // hi: all tiles; lo active kt < 2p+2
    const int nlo = 2 * p + 2;

    // one K-iteration; LO folds at compile time per call site
    auto body = [&](int kt, bool LO) {
        const int cb = kt & 1;
        if (kt + 1 < nkt) {              // prefetch next tile into other buffer
            glds16(kdma + (size_t)(kt + 1) * 2048, &Kbuf[cb ^ 1][wave * 512]);
            glds16(vdma + (kt + 1) * 32,           &Vbuf[cb ^ 1][wave * 512]);
        }
        f32x4 sh[2], sl[2];
#pragma unroll
        for (int mt = 0; mt < 2; ++mt) { sh[mt] = (f32x4)0.f; if (LO) sl[mt] = (f32x4)0.f; }
#pragma unroll
        for (int mt = 0; mt < 2; ++mt) {
            const __bf16* kr = &Kbuf[cb][(mt * 16 + l16) * 64];
#pragma unroll
            for (int kf = 0; kf < 2; ++kf) {
                bf16x8 ak = *(const bf16x8*)&kr[((((kf << 2) + quad) ^ (l16 & 7)) << 3)];
                sh[mt] = mfma16(ak, qh[kf], sh[mt]);     // S^T = K · Q^T
                if (LO) sl[mt] = mfma16(ak, ql[kf], sl[mt]);
            }
        }
        process(sh, kt >= 2 * tHi, kt * 32 - tHi * 64, oh, lh, cb);
        if (LO) process(sl, kt >= 2 * tLo, kt * 32 - tLo * 64, ol, ll, cb);
        __syncthreads();                 // next tile landed + all reads of cb done
    };

    __syncthreads();                     // tile 0 DMA drained
    int kt = 0;
    for (; kt < nlo; ++kt) body(kt, true);    // both tiles active
    for (; kt < nkt; ++kt) body(kt, false);   // hi only

    // ---- epilogue: O /= l (l from ones-MFMA; no shuffles) ----
    auto finish = [&](f32x4* oacc, f32x4& lacc, int trow) {
#pragma unroll
        for (int r = 0; r < 4; ++r) {
            float inv = 1.0f / lacc[r];
            float* op = Op + (size_t)(trow * 64 + wave * 16 + quad * 4 + r) * HD_;
#pragma unroll
            for (int nd = 0; nd < 4; ++nd)
                op[nd * 16 + l16] = oacc[nd][r] * inv;
        }
    };
    finish(oh, lh, tHi);
    finish(ol, ll, tLo);
}

// ---------- fallback (round-3 kernel) if ws too small ----------
#define LDAF 66
#define LDPF 68
__global__ __launch_bounds__(256, 4)
void fa_fwd_fb(const float* __restrict__ Qg, const float* __restrict__ Kg,
               const float* __restrict__ Vg, float* __restrict__ Og) {
    __shared__ __bf16 Ks[64 * LDAF];
    __shared__ __bf16 Vt[64 * LDAF];
    __shared__ __bf16 Psf[4 * 16 * LDPF];
    const int tid = threadIdx.x, lane = tid & 63, wave = tid >> 6;
    const int l16 = lane & 15, quad = lane >> 4;
    const int p = blockIdx.x & 15, tHi = 31 - p, tLo = p;
    const int bh = blockIdx.x >> 4, b = bh >> 4, h = bh & 15;
    const size_t base = (size_t)b * S_ * HD_ + (size_t)h * D_;
    const float* Qp = Qg + base; const float* Kp = Kg + base;
    const float* Vp = Vg + base; float* Op = Og + base;
    bf16x8 qh[2], ql[2];
#pragma unroll
    for (int kf = 0; kf < 2; ++kf) {
        const float* qph = Qp + (size_t)(tHi * 64 + wave * 16 + l16) * HD_ + quad * 8 + kf * 32;
        const float* qpl = Qp + (size_t)(tLo * 64 + wave * 16 + l16) * HD_ + quad * 8 + kf * 32;
        float4 x = *(const float4*)(qph); float4 y = *(const float4*)(qph + 4);
        bf16x8 f;
        f[0]=(__bf16)x.x; f[1]=(__bf16)x.y; f[2]=(__bf16)x.z; f[3]=(__bf16)x.w;
        f[4]=(__bf16)y.x; f[5]=(__bf16)y.y; f[6]=(__bf16)y.z; f[7]=(__bf16)y.w;
        qh[kf] = f;
        x = *(const float4*)(qpl); y = *(const float4*)(qpl + 4);
        f[0]=(__bf16)x.x; f[1]=(__bf16)x.y; f[2]=(__bf16)x.z; f[3]=(__bf16)x.w;
        f[4]=(__bf16)y.x; f[5]=(__bf16)y.y; f[6]=(__bf16)y.z; f[7]=(__bf16)y.w;
        ql[kf] = f;
    }
    f32x4 oh[4], ol[4]; float lh[4], ll[4];
#pragma unroll
    for (int nd = 0; nd < 4; ++nd) { oh[nd] = (f32x4)0.f; ol[nd] = (f32x4)0.f; }
#pragma unroll
    for (int r = 0; r < 4; ++r) { lh[r] = 0.f; ll[r] = 0.f; }
    auto process = [&](f32x4* s, bool diag, f32x4* oacc, float* lsum) {
#pragma unroll
        for (int nt = 0; nt < 4; ++nt)
#pragma unroll
            for (int r = 0; r < 4; ++r) {
                float v = s[nt][r] * SC_;
                if (diag && (nt * 16 + l16 > wave * 16 + quad * 4 + r)) v = -1e30f;
                float pe = __builtin_amdgcn_exp2f(v);
                s[nt][r] = pe; lsum[r] += pe;
            }
        __bf16* pw = &Psf[(wave * 16 + quad * 4) * LDPF + l16];
#pragma unroll
        for (int r = 0; r < 4; ++r)
#pragma unroll
            for (int nt = 0; nt < 4; ++nt) pw[r * LDPF + nt * 16] = (__bf16)s[nt][r];
        const __bf16* pr = &Psf[wave * 16 * LDPF];
#pragma unroll
        for (int kf = 0; kf < 2; ++kf) {
            bf16x8 a = *(const bf16x8*)&pr[l16 * LDPF + kf * 32 + quad * 8];
#pragma unroll
            for (int nd = 0; nd < 4; ++nd) {
                bf16x8 bv = *(const bf16x8*)&Vt[(nd * 16 + l16) * LDAF + kf * 32 + quad * 8];
                oacc[nd] = mfma16(a, bv, oacc[nd]);
            }
        }
    };
    const int nkt = 32 - p;
    for (int kt = 0; kt < nkt; ++kt) {
        __syncthreads();
#pragma unroll
        for (int rep = 0; rep < 4; ++rep) {
            int linear = rep * 256 + tid;
            int key = linear >> 4; int dq = (linear & 15) << 2;
            const float* kp = Kp + (size_t)(kt * 64 + key) * HD_ + dq;
            const float* vp = Vp + (size_t)(kt * 64 + key) * HD_ + dq;
            float4 kv = *(const float4*)kp; float4 vv = *(const float4*)vp;
            __bf16* kd = &Ks[key * LDAF + dq];
            kd[0]=(__bf16)kv.x; kd[1]=(__bf16)kv.y; kd[2]=(__bf16)kv.z; kd[3]=(__bf16)kv.w;
            Vt[(dq+0)*LDAF+key]=(__bf16)vv.x; Vt[(dq+1)*LDAF+key]=(__bf16)vv.y;
            Vt[(dq+2)*LDAF+key]=(__bf16)vv.z; Vt[(dq+3)*LDAF+key]=(__bf16)vv.w;
        }
        __syncthreads();
        const bool loAct = (kt <= p);
        f32x4 sh[4], sl[4];
#pragma unroll
        for (int nt = 0; nt < 4; ++nt) { sh[nt] = (f32x4)0.f; sl[nt] = (f32x4)0.f; }
#pragma unroll
        for (int nt = 0; nt < 4; ++nt)
#pragma unroll
            for (int kf = 0; kf < 2; ++kf) {
                bf16x8 bf = *(const bf16x8*)&Ks[(nt * 16 + l16) * LDAF + kf * 32 + quad * 8];
                sh[nt] = mfma16(qh[kf], bf, sh[nt]);
                if (loAct) sl[nt] = mfma16(ql[kf], bf, sl[nt]);
            }
        process(sh, kt == tHi, oh, lh);
        if (loAct) process(sl, kt == tLo, ol, ll);
    }
    auto finish = [&](f32x4* oacc, float* lsum, int trow) {
#pragma unroll
        for (int r = 0; r < 4; ++r) {
            float s = lsum[r];
            s += __shfl_xor(s, 1); s += __shfl_xor(s, 2);
            s += __shfl_xor(s, 4); s += __shfl_xor(s, 8);
            float inv = 1.0f / s;
            float* op = Op + (size_t)(trow * 64 + wave * 16 + quad * 4 + r) * HD_;
#pragma unroll
            for (int nd = 0; nd < 4; ++nd) op[nd * 16 + l16] = oacc[nd][r] * inv;
        }
    };
    finish(oh, lh, tHi); finish(ol, ll, tLo);
}

extern "C" void kernel_launch(void* const* d_in, const int* in_sizes, int n_in,
                              void* d_out, int out_size, void* d_ws, size_t ws_size,
                              hipStream_t stream) {
    const float* q = (const float*)d_in[0];
    const float* k = (const float*)d_in[1];
    const float* v = (const float*)d_in[2];
    float*       o = (float*)d_out;
    const size_t NEL  = (size_t)4 * H_ * S_ * D_;
    const size_t NEED = 2 * NEL * sizeof(__bf16);
    if (ws_size >= NEED) {
        __bf16* Kb  = (__bf16*)d_ws;
        __bf16* Vtb = Kb + NEL;
        dim3 pgrid(S_ / 64, 4 * H_, 2);
        prepack<<<pgrid, 256, 0, stream>>>(k, v, Kb, Vtb);
        fa_fwd<<<dim3(1024), 256, 0, stream>>>(q, Kb, Vtb, o);
    } else {
        fa_fwd_fb<<<dim3(1024), 256, 0, stream>>>(q, k, v, o);
    }
}